// Round 1
// baseline (3620.163 us; speedup 1.0000x reference)
//
#include <hip/hip_runtime.h>
#include <math.h>

#define NTHR 192
#define OBS 65   // per-thread LDS buffer stride in floats (65 -> conflict-free)

// Chunked matvec: out[off+q] = bias[off+q] (+ ob[off+q] if RESID) + sum_i in[i]*W[i*LDW+off+q]
// in: register array (compile-time indexed). W/bias: uniform -> s_load. Output -> per-thread LDS.
template<int K, int LDW, int N, bool RELU, bool RESID>
__device__ __forceinline__ void mv_obuf(const float (&in)[K],
                                        const float* __restrict__ W,
                                        const float* __restrict__ bias,
                                        float* ob) {
  #pragma unroll 1
  for (int off = 0; off < N; off += 4) {
    float a0 = bias[off+0];
    float a1 = bias[off+1];
    float a2 = bias[off+2];
    float a3 = bias[off+3];
    if (RESID) { a0 += ob[off+0]; a1 += ob[off+1]; a2 += ob[off+2]; a3 += ob[off+3]; }
    #pragma unroll
    for (int i = 0; i < K; ++i) {
      const float x = in[i];
      const float* wr = W + i*LDW + off;
      a0 = fmaf(x, wr[0], a0);
      a1 = fmaf(x, wr[1], a1);
      a2 = fmaf(x, wr[2], a2);
      a3 = fmaf(x, wr[3], a3);
    }
    if (RELU) { a0 = fmaxf(a0, 0.f); a1 = fmaxf(a1, 0.f); a2 = fmaxf(a2, 0.f); a3 = fmaxf(a3, 0.f); }
    ob[off+0] = a0; ob[off+1] = a1; ob[off+2] = a2; ob[off+3] = a3;
  }
}

// 64 -> 16 matvec straight into registers (for attention q/k/v slices).
template<int K, int LDW>
__device__ __forceinline__ void mv_r16(const float (&in)[K],
                                       const float* __restrict__ W,
                                       const float* __restrict__ bias,
                                       int colOff, float (&out)[16]) {
  #pragma unroll
  for (int q = 0; q < 16; ++q) out[q] = bias[colOff + q];
  #pragma unroll
  for (int i = 0; i < K; ++i) {
    const float x = in[i];
    const float* wr = W + i*LDW + colOff;
    #pragma unroll
    for (int q = 0; q < 16; ++q) out[q] = fmaf(x, wr[q], out[q]);
  }
}

template<int N>
__device__ __forceinline__ void readback(float (&dst)[N], const float* ob) {
  #pragma unroll
  for (int i = 0; i < N; ++i) dst[i] = ob[i];
}

__global__ __launch_bounds__(NTHR, 2) void flow_kernel(
    const float* __restrict__ x, const float* __restrict__ t, const float* __restrict__ y,
    const float* __restrict__ lp_w1, const float* __restrict__ lp_b1,
    const float* __restrict__ lp_w2, const float* __restrict__ lp_b2,
    const float* __restrict__ a1_win, const float* __restrict__ a1_bin,
    const float* __restrict__ a1_wout, const float* __restrict__ a1_bout,
    const float* __restrict__ a2_win, const float* __restrict__ a2_bin,
    const float* __restrict__ a2_wout, const float* __restrict__ a2_bout,
    const float* __restrict__ f1_gw, const float* __restrict__ f1_gb,
    const float* __restrict__ f1_bw, const float* __restrict__ f1_bb,
    const float* __restrict__ f2_gw, const float* __restrict__ f2_gb,
    const float* __restrict__ f2_bw, const float* __restrict__ f2_bb,
    const float* __restrict__ b1_w1, const float* __restrict__ b1_b1,
    const float* __restrict__ b1_w2, const float* __restrict__ b1_b2,
    const float* __restrict__ b2_w1, const float* __restrict__ b2_b1,
    const float* __restrict__ b2_w2, const float* __restrict__ b2_b2,
    const float* __restrict__ b3_w1, const float* __restrict__ b3_b1,
    const float* __restrict__ b3_w2, const float* __restrict__ b3_b2,
    const float* __restrict__ out_w, const float* __restrict__ out_b,
    float* __restrict__ out, int Btotal)
{
  __shared__ float smem[NTHR * OBS];
  float* ob = smem + (int)threadIdx.x * OBS;
  const int r = blockIdx.x * NTHR + threadIdx.x;
  if (r >= Btotal) return;

  // ---- inputs: x row + time features -> h80 (all compile-time indexed, stays in VGPRs)
  float h80[80];
  {
    const float4* xr = reinterpret_cast<const float4*>(x + (size_t)r * 64);
    #pragma unroll
    for (int c = 0; c < 16; ++c) {
      float4 v = xr[c];
      h80[4*c+0] = v.x; h80[4*c+1] = v.y; h80[4*c+2] = v.z; h80[4*c+3] = v.w;
    }
    const float tv = t[r];
    #pragma unroll
    for (int k = 0; k < 8; ++k) {
      const float fr = 3.14159265358979323846f * (float)(1 << k); // fp32(pi) * 2^k, exact
      const float arg = tv * fr;
      h80[64+k] = sinf(arg);
      h80[72+k] = cosf(arg);
    }
  }

  // ---- block1: h = relu(h80 @ b1_w1 + b1_b1) @ b1_w2 + b1_b2
  float h[64];
  mv_obuf<80,64,64,true,false>(h80, b1_w1, b1_b1, ob);
  readback(h, ob);
  mv_obuf<64,64,64,false,false>(h, b1_w2, b1_b2, ob);
  readback(h, ob);

  // ---- label projection: ye = relu(y @ lp_w1 + lp_b1) @ lp_w2 + lp_b2
  float ye[64];
  {
    float y40[40];
    const float4* yr = reinterpret_cast<const float4*>(y + (size_t)r * 40);
    #pragma unroll
    for (int c = 0; c < 10; ++c) {
      float4 v = yr[c];
      y40[4*c+0] = v.x; y40[4*c+1] = v.y; y40[4*c+2] = v.z; y40[4*c+3] = v.w;
    }
    mv_obuf<40,32,32,true,false>(y40, lp_w1, lp_b1, ob);
    float y32[32];
    readback(y32, ob);
    mv_obuf<32,64,64,false,false>(y32, lp_w2, lp_b2, ob);
    readback(ye, ob);
  }

  // ---- two repetitions of [attention, FiLM, residual block]
  #pragma unroll 1
  for (int rep = 0; rep < 2; ++rep) {
    const float* win  = rep ? a2_win  : a1_win;
    const float* bin  = rep ? a2_bin  : a1_bin;
    const float* wout = rep ? a2_wout : a1_wout;
    const float* bout = rep ? a2_bout : a1_bout;
    const float* gwp  = rep ? f2_gw : f1_gw;
    const float* gbp  = rep ? f2_gb : f1_gb;
    const float* bwp  = rep ? f2_bw : f1_bw;
    const float* bbp  = rep ? f2_bb : f1_bb;
    const float* w1p  = rep ? b3_w1 : b2_w1;
    const float* b1p  = rep ? b3_b1 : b2_b1;
    const float* w2p  = rep ? b3_w2 : b2_w2;
    const float* b2p  = rep ? b3_b2 : b2_b2;

    // Attention on seq=[h, ye], only token-0 output needed. Accumulate out-proj in ob[0..64).
    #pragma unroll 1
    for (int hd = 0; hd < 4; ++hd) {
      const int c0 = hd * 16;
      float q0[16], k0[16], k1[16];
      mv_r16<64,192>(h,  win, bin, c0,      q0);
      mv_r16<64,192>(h,  win, bin, 64 + c0, k0);
      mv_r16<64,192>(ye, win, bin, 64 + c0, k1);
      float s0 = 0.f, s1 = 0.f;
      #pragma unroll
      for (int d = 0; d < 16; ++d) { s0 = fmaf(q0[d], k0[d], s0); s1 = fmaf(q0[d], k1[d], s1); }
      s0 *= 0.25f; s1 *= 0.25f;
      const float mx = fmaxf(s0, s1);
      const float e0 = __expf(s0 - mx), e1 = __expf(s1 - mx);
      const float inv = 1.f / (e0 + e1);
      const float p0 = e0 * inv, p1 = e1 * inv;
      float v0[16], v1[16];
      mv_r16<64,192>(h,  win, bin, 128 + c0, v0);
      mv_r16<64,192>(ye, win, bin, 128 + c0, v1);
      float ov[16];
      #pragma unroll
      for (int d = 0; d < 16; ++d) ov[d] = fmaf(p0, v0[d], p1 * v1[d]);
      // out-proj partial: ob[j] (+)= sum_d ov[d] * wout[(c0+d)*64 + j]
      #pragma unroll 1
      for (int off = 0; off < 64; off += 4) {
        float a0, a1v, a2v, a3;
        if (hd == 0) { a0 = bout[off]; a1v = bout[off+1]; a2v = bout[off+2]; a3 = bout[off+3]; }
        else         { a0 = ob[off];   a1v = ob[off+1];   a2v = ob[off+2];   a3 = ob[off+3]; }
        #pragma unroll
        for (int d = 0; d < 16; ++d) {
          const float* wr = wout + (c0 + d) * 64 + off;
          const float o = ov[d];
          a0  = fmaf(o, wr[0], a0);
          a1v = fmaf(o, wr[1], a1v);
          a2v = fmaf(o, wr[2], a2v);
          a3  = fmaf(o, wr[3], a3);
        }
        ob[off+0] = a0; ob[off+1] = a1v; ob[off+2] = a2v; ob[off+3] = a3;
      }
    }

    // FiLM (in-place on ob): ob[j] = (ye@gw+gb)[j] * ob[j] + (ye@bw+bb)[j]
    #pragma unroll 1
    for (int off = 0; off < 64; off += 4) {
      float g0 = gbp[off], g1 = gbp[off+1], g2 = gbp[off+2], g3 = gbp[off+3];
      float f0 = bbp[off], f1 = bbp[off+1], f2 = bbp[off+2], f3 = bbp[off+3];
      #pragma unroll
      for (int i = 0; i < 64; ++i) {
        const float yv = ye[i];
        const float* gr = gwp + i*64 + off;
        const float* br = bwp + i*64 + off;
        g0 = fmaf(yv, gr[0], g0); g1 = fmaf(yv, gr[1], g1);
        g2 = fmaf(yv, gr[2], g2); g3 = fmaf(yv, gr[3], g3);
        f0 = fmaf(yv, br[0], f0); f1 = fmaf(yv, br[1], f1);
        f2 = fmaf(yv, br[2], f2); f3 = fmaf(yv, br[3], f3);
      }
      ob[off+0] = fmaf(g0, ob[off+0], f0);
      ob[off+1] = fmaf(g1, ob[off+1], f1);
      ob[off+2] = fmaf(g2, ob[off+2], f2);
      ob[off+3] = fmaf(g3, ob[off+3], f3);
    }
    readback(h, ob);   // h = FiLM output

    // Residual block: h = h + relu(h@w1+b1) @ w2 + b2
    mv_obuf<64,64,64,true,false>(h, w1p, b1p, ob);   // ob = u
    #pragma unroll
    for (int i = 0; i < 64; ++i) { const float u = ob[i]; ob[i] = h[i]; h[i] = u; } // swap: h=u, ob=h_old
    mv_obuf<64,64,64,false,true>(h, w2p, b2p, ob);   // ob = h_old + u@w2 + b2
    readback(h, ob);
  }

  // ---- final projection + store
  mv_obuf<64,64,64,false,false>(h, out_w, out_b, ob);
  {
    float4* orow = reinterpret_cast<float4*>(out + (size_t)r * 64);
    #pragma unroll
    for (int c = 0; c < 16; ++c) {
      float4 v;
      v.x = ob[4*c+0]; v.y = ob[4*c+1]; v.z = ob[4*c+2]; v.w = ob[4*c+3];
      orow[c] = v;
    }
  }
}

extern "C" void kernel_launch(void* const* d_in, const int* in_sizes, int n_in,
                              void* d_out, int out_size, void* d_ws, size_t ws_size,
                              hipStream_t stream) {
  (void)n_in; (void)out_size; (void)d_ws; (void)ws_size;
  const float* p[37];
  for (int i = 0; i < 37; ++i) p[i] = (const float*)d_in[i];
  const int B = in_sizes[0] / 64;
  const int grid = (B + NTHR - 1) / NTHR;
  flow_kernel<<<dim3(grid), dim3(NTHR), 0, stream>>>(
      p[0],  p[1],  p[2],
      p[3],  p[4],  p[5],  p[6],
      p[7],  p[8],  p[9],  p[10],
      p[11], p[12], p[13], p[14],
      p[15], p[16], p[17], p[18],
      p[19], p[20], p[21], p[22],
      p[23], p[24], p[25], p[26],
      p[27], p[28], p[29], p[30],
      p[31], p[32], p[33], p[34],
      p[35], p[36],
      (float*)d_out, B);
}

// Round 2
// 269.320 us; speedup vs baseline: 13.4418x; 13.4418x over previous
//
#include <hip/hip_runtime.h>
#include <math.h>

typedef __attribute__((ext_vector_type(8))) short short8;   // 8 bf16 = 4 VGPRs (MFMA A/B frag)
typedef __attribute__((ext_vector_type(4))) float f32x4;    // MFMA C/D frag

#define MFMA16(a,b,c) __builtin_amdgcn_mfma_f32_16x16x32_bf16((a),(b),(c),0,0,0)

// ---- ws layout: 164 frag-blocks of 1024 B (64 lanes x 16 B) ----
#define WS_B1W1   0
#define WS_B1W2   12
#define WS_LPW1   20
#define WS_LPW2   24
#define WS_A1WIN  28
#define WS_A1WOUT 52
#define WS_F1GW   60
#define WS_F1BW   68
#define WS_B2W1   76
#define WS_B2W2   84
#define WS_A2WIN  92
#define WS_A2WOUT 116
#define WS_F2GW   124
#define WS_F2BW   132
#define WS_B3W1   140
#define WS_B3W2   148
#define WS_OUTW   156
#define WS_FRAGS  164

__device__ __forceinline__ unsigned short f2bf(float f) {
  unsigned int u = __float_as_uint(f);
  u = (u + 0x7fffu + ((u >> 16) & 1u)) >> 16;   // RNE
  return (unsigned short)u;
}

__device__ __forceinline__ short8 pack8(float4 a, float4 b) {
  short8 r;
  r[0]=(short)f2bf(a.x); r[1]=(short)f2bf(a.y); r[2]=(short)f2bf(a.z); r[3]=(short)f2bf(a.w);
  r[4]=(short)f2bf(b.x); r[5]=(short)f2bf(b.y); r[6]=(short)f2bf(b.z); r[7]=(short)f2bf(b.w);
  return r;
}

__device__ __forceinline__ short8 zero8() {
  short8 r;
  #pragma unroll
  for (int j = 0; j < 8; ++j) r[j] = 0;
  return r;
}

// ============ prep: weights f32 -> bf16 B-fragments in d_ws ============
// B-frag layout (16x16x32): lane l holds B[k = (l>>4)*8 + j][col = l&15], j=0..7.
// Frag-block f of a matrix: n = f / kc (16-col tile), c = f % kc (32-k chunk).
__global__ __launch_bounds__(64) void prep_kernel(
    const float* b1w1, const float* b1w2, const float* lpw1, const float* lpw2,
    const float* a1win, const float* a1wout, const float* f1gw, const float* f1bw,
    const float* b2w1, const float* b2w2, const float* a2win, const float* a2wout,
    const float* f2gw, const float* f2bw, const float* b3w1, const float* b3w2,
    const float* outw, unsigned short* ws)
{
  const float* WS_[17] = {b1w1,b1w2,lpw1,lpw2,a1win,a1wout,f1gw,f1bw,b2w1,b2w2,
                          a2win,a2wout,f2gw,f2bw,b3w1,b3w2,outw};
  const int KA[17] = {80,64,40,32,64,64,64,64,64,64,64,64,64,64,64,64,64};
  const int NA[17] = {64,64,32,64,192,64,64,64,64,64,192,64,64,64,64,64,64};
  const int FO[17] = {0,12,20,24,28,52,60,68,76,84,92,116,124,132,140,148,156};

  const int b = blockIdx.x;
  int m = 0;
  #pragma unroll
  for (int i = 1; i < 17; ++i) if (b >= FO[i]) m = i;
  const int f  = b - FO[m];
  const int K  = KA[m], N = NA[m];
  const int kc = (K + 31) >> 5;
  const int n  = f / kc, c = f % kc;

  const int lane = threadIdx.x;
  const int col  = n * 16 + (lane & 15);
  const int kb   = c * 32 + ((lane >> 4) * 8);
  const float* W = WS_[m];

  short8 r;
  #pragma unroll
  for (int j = 0; j < 8; ++j) {
    const int k = kb + j;
    const float v = (k < K) ? W[(size_t)k * N + col] : 0.0f;
    r[j] = (short)f2bf(v);
  }
  *reinterpret_cast<short8*>(ws + (size_t)b * 512 + lane * 8) = r;
}

// ============ main kernel helpers ============
// LDS tile per wave: 16 rows x stride 72 bf16 (rows = batch rows, cols = feature).
__device__ __forceinline__ short8 ldA(const unsigned short* L, int c, int lrow, int grp) {
  return *reinterpret_cast<const short8*>(L + lrow * 72 + c * 32 + grp * 8);
}
__device__ __forceinline__ void stC(unsigned short* L, int n, int lrow, int grp, f32x4 v) {
  unsigned short* p = L + (grp * 4) * 72 + n * 16 + lrow;
  p[0]   = f2bf(v[0]);
  p[72]  = f2bf(v[1]);
  p[144] = f2bf(v[2]);
  p[216] = f2bf(v[3]);
}
__device__ __forceinline__ f32x4 relu4(f32x4 v) {
  f32x4 r;
  #pragma unroll
  for (int j = 0; j < 4; ++j) r[j] = fmaxf(v[j], 0.0f);
  return r;
}
__device__ __forceinline__ f32x4 gemm1(short8 a0, const short8* wsl, int fb, float bias) {
  f32x4 acc = {bias, bias, bias, bias};
  acc = MFMA16(a0, wsl[fb * 64], acc);
  return acc;
}
__device__ __forceinline__ f32x4 gemm2(short8 a0, short8 a1, const short8* wsl, int fb, float bias) {
  f32x4 acc = {bias, bias, bias, bias};
  acc = MFMA16(a0, wsl[(fb + 0) * 64], acc);
  acc = MFMA16(a1, wsl[(fb + 1) * 64], acc);
  return acc;
}
__device__ __forceinline__ f32x4 gemm3(short8 a0, short8 a1, short8 a2, const short8* wsl, int fb, float bias) {
  f32x4 acc = {bias, bias, bias, bias};
  acc = MFMA16(a0, wsl[(fb + 0) * 64], acc);
  acc = MFMA16(a1, wsl[(fb + 1) * 64], acc);
  acc = MFMA16(a2, wsl[(fb + 2) * 64], acc);
  return acc;
}

// ============ main kernel: 4 waves/block, 16 rows/wave ============
__global__ __launch_bounds__(256, 3) void flow_mfma(
    const float* __restrict__ x, const float* __restrict__ t, const float* __restrict__ y,
    const float* __restrict__ b1b1, const float* __restrict__ b1b2,
    const float* __restrict__ lpb1, const float* __restrict__ lpb2,
    const float* __restrict__ a1bin, const float* __restrict__ a1bout,
    const float* __restrict__ f1gb, const float* __restrict__ f1bb,
    const float* __restrict__ b2b1, const float* __restrict__ b2b2,
    const float* __restrict__ a2bin, const float* __restrict__ a2bout,
    const float* __restrict__ f2gb, const float* __restrict__ f2bb,
    const float* __restrict__ b3b1, const float* __restrict__ b3b2,
    const float* __restrict__ outb,
    const unsigned short* __restrict__ ws,
    float* __restrict__ out, int Btotal)
{
  __shared__ __align__(16) unsigned short lds[4][16 * 72];
  const int tid  = threadIdx.x;
  const int lane = tid & 63, wid = tid >> 6;
  const int lrow = lane & 15, grp = lane >> 4;
  const int r0   = (blockIdx.x * 4 + wid) * 16;
  if (r0 >= Btotal) return;
  unsigned short* L = &lds[wid][0];
  const short8* wsl = reinterpret_cast<const short8*>(ws) + lane;

  // ---- h80 A-frags: x (chunks 0,1) + time features (chunk 2, zero-padded 80..95)
  short8 hA0, hA1, hA2;
  {
    const float4* xp = reinterpret_cast<const float4*>(x + (size_t)(r0 + lrow) * 64) + grp * 2;
    hA0 = pack8(xp[0], xp[1]);
    hA1 = pack8(xp[8], xp[9]);
    const float tv = t[r0 + lrow];
    float v8[8];
    if (grp == 0) {
      #pragma unroll
      for (int j = 0; j < 8; ++j) v8[j] = sinf(tv * (3.14159265358979323846f * (float)(1 << j)));
    } else if (grp == 1) {
      #pragma unroll
      for (int j = 0; j < 8; ++j) v8[j] = cosf(tv * (3.14159265358979323846f * (float)(1 << j)));
    } else {
      #pragma unroll
      for (int j = 0; j < 8; ++j) v8[j] = 0.0f;
    }
    #pragma unroll
    for (int j = 0; j < 8; ++j) hA2[j] = (short)f2bf(v8[j]);
  }

  // ---- block1: h = relu(h80@b1_w1+b1) @ b1_w2 + b2
  #pragma unroll
  for (int n = 0; n < 4; ++n)
    stC(L, n, lrow, grp, relu4(gemm3(hA0, hA1, hA2, wsl, WS_B1W1 + n * 3, b1b1[n * 16 + lrow])));
  {
    const short8 u0 = ldA(L, 0, lrow, grp), u1 = ldA(L, 1, lrow, grp);
    #pragma unroll
    for (int n = 0; n < 4; ++n)
      stC(L, n, lrow, grp, gemm2(u0, u1, wsl, WS_B1W2 + n * 2, b1b2[n * 16 + lrow]));
  }
  hA0 = ldA(L, 0, lrow, grp);   // h after block1, A-form (reuse regs)
  hA1 = ldA(L, 1, lrow, grp);

  // ---- label projection: ye = relu(y@lp_w1+b1) @ lp_w2 + b2
  short8 yeA0, yeA1;
  {
    const float* yrow = y + (size_t)(r0 + lrow) * 40;
    const short8 y0 = pack8(*reinterpret_cast<const float4*>(yrow + grp * 8),
                            *reinterpret_cast<const float4*>(yrow + grp * 8 + 4));
    short8 y1 = zero8();
    if (grp == 0)
      y1 = pack8(*reinterpret_cast<const float4*>(yrow + 32),
                 *reinterpret_cast<const float4*>(yrow + 36));
    #pragma unroll
    for (int n = 0; n < 2; ++n)
      stC(L, n, lrow, grp, relu4(gemm2(y0, y1, wsl, WS_LPW1 + n * 2, lpb1[n * 16 + lrow])));
    const short8 z = ldA(L, 0, lrow, grp);
    #pragma unroll
    for (int n = 0; n < 4; ++n)
      stC(L, n, lrow, grp, gemm1(z, wsl, WS_LPW2 + n, lpb2[n * 16 + lrow]));
    yeA0 = ldA(L, 0, lrow, grp);
    yeA1 = ldA(L, 1, lrow, grp);
  }

  // ---- two reps of [attention -> FiLM -> residual block]
  f32x4 hC0, hC1, hC2, hC3;    // C-form copy of current h (for residual)
  #pragma unroll 1
  for (int rep = 0; rep < 2; ++rep) {
    const int WIN  = rep ? WS_A2WIN  : WS_A1WIN;
    const int WOUT = rep ? WS_A2WOUT : WS_A1WOUT;
    const int GW   = rep ? WS_F2GW   : WS_F1GW;
    const int BW   = rep ? WS_F2BW   : WS_F1BW;
    const int W1   = rep ? WS_B3W1   : WS_B2W1;
    const int W2   = rep ? WS_B3W2   : WS_B2W2;
    const float* binp  = rep ? a2bin  : a1bin;
    const float* boutp = rep ? a2bout : a1bout;
    const float* gbp   = rep ? f2gb   : f1gb;
    const float* fbp   = rep ? f2bb   : f1bb;
    const float* w1b   = rep ? b3b1   : b2b1;
    const float* w2b   = rep ? b3b2   : b2b2;

    // attention: per head n (= 16-col tile n). Only token-0 output needed.
    #pragma unroll 1
    for (int n = 0; n < 4; ++n) {
      const f32x4 q  = gemm2(hA0,  hA1,  wsl, WIN + n * 2,        binp[n * 16 + lrow]);
      const f32x4 k0 = gemm2(hA0,  hA1,  wsl, WIN + (4 + n) * 2,  binp[64 + n * 16 + lrow]);
      const f32x4 k1 = gemm2(yeA0, yeA1, wsl, WIN + (4 + n) * 2,  binp[64 + n * 16 + lrow]);
      const f32x4 v0 = gemm2(hA0,  hA1,  wsl, WIN + (8 + n) * 2,  binp[128 + n * 16 + lrow]);
      const f32x4 v1 = gemm2(yeA0, yeA1, wsl, WIN + (8 + n) * 2,  binp[128 + n * 16 + lrow]);
      f32x4 ov;
      #pragma unroll
      for (int j = 0; j < 4; ++j) {          // j -> batch row grp*4+j
        float s0 = q[j] * k0[j];
        float s1 = q[j] * k1[j];
        #pragma unroll
        for (int mk = 1; mk <= 8; mk <<= 1) {  // reduce over the 16 head dims (lanes)
          s0 += __shfl_xor(s0, mk);
          s1 += __shfl_xor(s1, mk);
        }
        s0 *= 0.25f; s1 *= 0.25f;              // 1/sqrt(16)
        const float mx = fmaxf(s0, s1);
        const float e0 = __expf(s0 - mx), e1 = __expf(s1 - mx);
        const float inv = 1.0f / (e0 + e1);
        ov[j] = (e0 * v0[j] + e1 * v1[j]) * inv;
      }
      stC(L, n, lrow, grp, ov);
    }
    const short8 oA0 = ldA(L, 0, lrow, grp), oA1 = ldA(L, 1, lrow, grp);

    // out-proj + FiLM fused per tile (manual unroll to keep hC in named regs)
    {
      f32x4 at, g, bb;
      at = gemm2(oA0, oA1, wsl, WOUT + 0, boutp[lrow]);
      g  = gemm2(yeA0, yeA1, wsl, GW + 0, gbp[lrow]);
      bb = gemm2(yeA0, yeA1, wsl, BW + 0, fbp[lrow]);
      #pragma unroll
      for (int j = 0; j < 4; ++j) hC0[j] = fmaf(g[j], at[j], bb[j]);
      stC(L, 0, lrow, grp, hC0);
      at = gemm2(oA0, oA1, wsl, WOUT + 2, boutp[16 + lrow]);
      g  = gemm2(yeA0, yeA1, wsl, GW + 2, gbp[16 + lrow]);
      bb = gemm2(yeA0, yeA1, wsl, BW + 2, fbp[16 + lrow]);
      #pragma unroll
      for (int j = 0; j < 4; ++j) hC1[j] = fmaf(g[j], at[j], bb[j]);
      stC(L, 1, lrow, grp, hC1);
      at = gemm2(oA0, oA1, wsl, WOUT + 4, boutp[32 + lrow]);
      g  = gemm2(yeA0, yeA1, wsl, GW + 4, gbp[32 + lrow]);
      bb = gemm2(yeA0, yeA1, wsl, BW + 4, fbp[32 + lrow]);
      #pragma unroll
      for (int j = 0; j < 4; ++j) hC2[j] = fmaf(g[j], at[j], bb[j]);
      stC(L, 2, lrow, grp, hC2);
      at = gemm2(oA0, oA1, wsl, WOUT + 6, boutp[48 + lrow]);
      g  = gemm2(yeA0, yeA1, wsl, GW + 6, gbp[48 + lrow]);
      bb = gemm2(yeA0, yeA1, wsl, BW + 6, fbp[48 + lrow]);
      #pragma unroll
      for (int j = 0; j < 4; ++j) hC3[j] = fmaf(g[j], at[j], bb[j]);
      stC(L, 3, lrow, grp, hC3);
    }

    // residual block: h = h + relu(h@w1+b1) @ w2 + b2
    const short8 fA0 = ldA(L, 0, lrow, grp), fA1 = ldA(L, 1, lrow, grp);
    #pragma unroll
    for (int n = 0; n < 4; ++n)
      stC(L, n, lrow, grp, relu4(gemm2(fA0, fA1, wsl, W1 + n * 2, w1b[n * 16 + lrow])));
    const short8 uA0 = ldA(L, 0, lrow, grp), uA1 = ldA(L, 1, lrow, grp);
    {
      f32x4 a;
      a = gemm2(uA0, uA1, wsl, W2 + 0, w2b[lrow]);
      #pragma unroll
      for (int j = 0; j < 4; ++j) a[j] += hC0[j];
      stC(L, 0, lrow, grp, a);
      a = gemm2(uA0, uA1, wsl, W2 + 2, w2b[16 + lrow]);
      #pragma unroll
      for (int j = 0; j < 4; ++j) a[j] += hC1[j];
      stC(L, 1, lrow, grp, a);
      a = gemm2(uA0, uA1, wsl, W2 + 4, w2b[32 + lrow]);
      #pragma unroll
      for (int j = 0; j < 4; ++j) a[j] += hC2[j];
      stC(L, 2, lrow, grp, a);
      a = gemm2(uA0, uA1, wsl, W2 + 6, w2b[48 + lrow]);
      #pragma unroll
      for (int j = 0; j < 4; ++j) a[j] += hC3[j];
      stC(L, 3, lrow, grp, a);
    }
    hA0 = ldA(L, 0, lrow, grp);
    hA1 = ldA(L, 1, lrow, grp);
  }

  // ---- final projection + store
  float* obase = out + (size_t)r0 * 64;
  #pragma unroll 1
  for (int n = 0; n < 4; ++n) {
    const f32x4 a = gemm2(hA0, hA1, wsl, WS_OUTW + n * 2, outb[n * 16 + lrow]);
    #pragma unroll
    for (int j = 0; j < 4; ++j)
      obase[(grp * 4 + j) * 64 + n * 16 + lrow] = a[j];
  }
}

extern "C" void kernel_launch(void* const* d_in, const int* in_sizes, int n_in,
                              void* d_out, int out_size, void* d_ws, size_t ws_size,
                              hipStream_t stream) {
  (void)n_in; (void)out_size; (void)ws_size;
  const float* p[37];
  for (int i = 0; i < 37; ++i) p[i] = (const float*)d_in[i];
  unsigned short* ws = (unsigned short*)d_ws;

  prep_kernel<<<dim3(WS_FRAGS), dim3(64), 0, stream>>>(
      p[23], p[25], p[3], p[5], p[7], p[9], p[15], p[17],
      p[27], p[29], p[11], p[13], p[19], p[21], p[31], p[33], p[35], ws);

  const int B = in_sizes[0] / 64;
  const int grid = (B + 63) / 64;
  flow_mfma<<<dim3(grid), dim3(256), 0, stream>>>(
      p[0], p[1], p[2],
      p[24], p[26],          // b1_b1, b1_b2
      p[4],  p[6],           // lp_b1, lp_b2
      p[8],  p[10],          // a1_bin, a1_bout
      p[16], p[18],          // f1_gb, f1_bb
      p[28], p[30],          // b2_b1, b2_b2
      p[12], p[14],          // a2_bin, a2_bout
      p[20], p[22],          // f2_gb, f2_bb
      p[32], p[34],          // b3_b1, b3_b2
      p[36],                 // out_b
      ws, (float*)d_out, B);
}